// Round 4
// baseline (414.744 us; speedup 1.0000x reference)
//
#include <hip/hip_runtime.h>
#include <math.h>

typedef _Float16 f16;
typedef f16 f16x8 __attribute__((ext_vector_type(8)));
typedef float f32x4 __attribute__((ext_vector_type(4)));

#define N_ROWS 32768
#define DIM    256
#define KCODES 4096

// ws layout (float units)
#define WS_ET    0                           // et [4096][256] f32        (4 MB)
#define WS_BN    (WS_ET + KCODES*DIM)        // code norms [4096]
#define WS_AN    (WS_BN + KCODES)            // row norms [32768]
#define WS_PART  (WS_AN + N_ROWS)            // loss partials [8192]
#define WS_BEST  (WS_PART + 8192)            // u64 bests [32768] = 65536 floats
#define WS_BP    (WS_BEST + 65536)           // B' images  4 MB = 1048576 floats
#define WS_AP    (WS_BP + 1048576)           // A' images 32 MB = 8388608 floats

// Image geometry: one chunk = [128 rows][64 f16 = 128 B], swizzled:
//   byte_in_row = (dd*2) ^ ((row & 7) << 4)
// Per-rb A' block: 131072 B  (H plane @0: 4 chunks x 16384; L plane @65536)
// Per-jb B' block: 131072 B  (EH plane @0; EL plane @65536)
//
// sim*2^20 = H.EH + L.EH + H.EL  -> 12 uniform BK=64 chunks:
//   c in [0,4):  A=H chunk c,   B=EH chunk c
//   c in [4,8):  A=L chunk c-4, B=EH chunk c-4
//   c in [8,12): A=H chunk c-8, B=EL chunk c-8

// ---------------------------------------------------------------- helpers
__device__ __forceinline__ void gload16(const void* g, void* l) {
#if __has_builtin(__builtin_amdgcn_global_load_lds)
    __builtin_amdgcn_global_load_lds(
        (const __attribute__((address_space(1))) unsigned int*)g,
        (__attribute__((address_space(3))) unsigned int*)l, 16, 0, 0);
#else
    *(float4*)l = *(const float4*)g;
#endif
}

__device__ __forceinline__ int aoff_of(int c) {
    return (c & 3) * 16384 + (((c >> 2) == 1) ? 65536 : 0);
}
__device__ __forceinline__ int boff_of(int c) {
    return (c & 3) * 16384 + (((c >> 2) == 2) ? 65536 : 0);
}

// ---------------------------------------------------------------- transpose (for gather + bn)
__global__ void vq_transpose(const float* __restrict__ e, float* __restrict__ et) {
    __shared__ float tile[32][33];
    int x = threadIdx.x & 31;
    int y = threadIdx.x >> 5;
    int k0 = blockIdx.x * 32;
    int d0 = blockIdx.y * 32;
#pragma unroll
    for (int yy = 0; yy < 32; yy += 8)
        tile[y + yy][x] = e[(d0 + y + yy) * KCODES + k0 + x];
    __syncthreads();
#pragma unroll
    for (int yy = 0; yy < 32; yy += 8)
        et[(k0 + y + yy) * DIM + d0 + x] = tile[x][y + yy];
}

// ---------------------------------------------------------------- row norms (codes only now)
__global__ void vq_rownorm(const float* __restrict__ src, float* __restrict__ out, int nrows) {
    int w    = threadIdx.x >> 6;
    int lane = threadIdx.x & 63;
    int row  = blockIdx.x * 4 + w;
    if (row >= nrows) return;
    float4 v = *(const float4*)&src[row * DIM + lane * 4];
    float  s = v.x * v.x + v.y * v.y + v.z * v.z + v.w * v.w;
#pragma unroll
    for (int m = 1; m < 64; m <<= 1) s += __shfl_xor(s, m);
    if (lane == 0) out[row] = s;
}

// ---------------------------------------------------------------- A' prep (+ fused x row norms)
// x [32768][256] f32 -> per-rb swizzled H/L chunk images; one wave covers one row.
__global__ void vq_prep_a(const float* __restrict__ x, char* __restrict__ Ap,
                          float* __restrict__ An) {
    const int t = threadIdx.x;
    const int lane = t & 63, w = t >> 6;
    const size_t row0 = (size_t)blockIdx.x * 128;
    char* base = Ap + (size_t)blockIdx.x * 131072;
    const int chunk = lane >> 4;
    const int dd2   = (lane & 15) * 8;       // byte offset of 4 f16
#pragma unroll 4
    for (int it = 0; it < 32; ++it) {
        const int m = it * 4 + w;
        float4 v = *(const float4*)&x[(row0 + m) * DIM + lane * 4];
        float vs[4] = { v.x, v.y, v.z, v.w };
        uint32_t hw[2], lw[2];
#pragma unroll
        for (int p = 0; p < 2; ++p) {
            uint32_t hword = 0, lword = 0;
#pragma unroll
            for (int j = 0; j < 2; ++j) {
                float s = vs[p * 2 + j] * 1024.0f;
                f16 h = (f16)s;
                f16 l = (f16)(s - (float)h);
                hword |= (uint32_t)__builtin_bit_cast(uint16_t, h) << (16 * j);
                lword |= (uint32_t)__builtin_bit_cast(uint16_t, l) << (16 * j);
            }
            hw[p] = hword; lw[p] = lword;
        }
        const int off = chunk * 16384 + m * 128 + (dd2 ^ ((m & 7) << 4));
        *(uint2*)(base + off)         = *(uint2*)hw;
        *(uint2*)(base + 65536 + off) = *(uint2*)lw;
        // fused row norm
        float s = v.x * v.x + v.y * v.y + v.z * v.z + v.w * v.w;
#pragma unroll
        for (int mm = 1; mm < 64; mm <<= 1) s += __shfl_xor(s, mm);
        if (lane == 0) An[row0 + m] = s;
    }
}

// ---------------------------------------------------------------- B' prep
__global__ void vq_prep_b(const float* __restrict__ e, char* __restrict__ Bp) {
    __shared__ float lt[128][65];   // [n_loc][dd]
    const int t  = threadIdx.x;
    const int jb = blockIdx.x >> 2;
    const int c  = blockIdx.x & 3;
    const int d0 = c * 64, n0 = jb * 128;
#pragma unroll
    for (int it = 0; it < 8; ++it) {
        int linear = it * 256 + t;
        int drow = linear >> 5;
        int ncol = (linear & 31) * 4;
        float4 v = *(const float4*)&e[(size_t)(d0 + drow) * KCODES + n0 + ncol];
        lt[ncol + 0][drow] = v.x;
        lt[ncol + 1][drow] = v.y;
        lt[ncol + 2][drow] = v.z;
        lt[ncol + 3][drow] = v.w;
    }
    __syncthreads();
    char* ehbase = Bp + (size_t)jb * 131072 + c * 16384;
    const int n_loc = t >> 1;
    const int shalf = t & 1;
#pragma unroll
    for (int g = 0; g < 4; ++g) {
        const int dd8 = shalf * 32 + g * 8;
        uint32_t ehw[4], elw[4];
#pragma unroll
        for (int p = 0; p < 4; ++p) {
            uint32_t hword = 0, lword = 0;
#pragma unroll
            for (int j = 0; j < 2; ++j) {
                float s = lt[n_loc][dd8 + p * 2 + j] * 1024.0f;
                f16 h = (f16)s;
                f16 l = (f16)(s - (float)h);
                hword |= (uint32_t)__builtin_bit_cast(uint16_t, h) << (16 * j);
                lword |= (uint32_t)__builtin_bit_cast(uint16_t, l) << (16 * j);
            }
            ehw[p] = hword; elw[p] = lword;
        }
        const int off = n_loc * 128 + ((dd8 * 2) ^ ((n_loc & 7) << 4));
        *(uint4*)(ehbase + off)         = *(uint4*)ehw;
        *(uint4*)(ehbase + 65536 + off) = *(uint4*)elw;
    }
}

// ---------------------------------------------------------------- init bests
__global__ void vq_init(unsigned long long* __restrict__ bests) {
    int i = blockIdx.x * 256 + threadIdx.x;
    if (i < N_ROWS) bests[i] = ~0ull;
}

// ---------------------------------------------------------------- main MFMA GEMM + argmin
// 128x128 tile, uniform K'=768 as 12 BK=64 chunks, double-buffered LDS,
// 2-phase pipeline: stage(c+1) -> compute(c) -> one barrier per chunk.
__global__ __launch_bounds__(256) void vq_main(
    const char* __restrict__ Ap, const char* __restrict__ Bp,
    const float* __restrict__ An, const float* __restrict__ Bn,
    unsigned long long* __restrict__ bests)
{
    __shared__ __align__(16) char As[2][16384];
    __shared__ __align__(16) char Bs[2][16384];

    const int tid  = threadIdx.x;
    const int wid  = tid >> 6, lane = tid & 63;
    const int wr   = wid >> 1, wc = wid & 1;
    const int rb   = blockIdx.x & 255, jb = blockIdx.x >> 8;
    const int row0 = rb * 128, c0 = jb * 128;
    const int hi = lane >> 4, ln = lane & 15;
    const int sx = (lane & 7) << 4;

    const char* abase = Ap + (size_t)rb * 131072;
    const char* bbase = Bp + (size_t)jb * 131072;

    f32x4 acc[4][4] = {};

    // prologue: stage chunk 0 into buf 0
#pragma unroll
    for (int it = 0; it < 4; ++it) {
        const int o = it * 4096 + tid * 16;
        gload16(abase + o, As[0] + o);
        gload16(bbase + o, Bs[0] + o);
    }
    __syncthreads();

#pragma unroll
    for (int c = 0; c < 12; ++c) {
        const int cur = c & 1;
        // issue next-chunk loads first (in flight under this chunk's MFMA)
        if (c < 11) {
            const int ao = aoff_of(c + 1), bo = boff_of(c + 1);
#pragma unroll
            for (int it = 0; it < 4; ++it) {
                const int o = it * 4096 + tid * 16;
                gload16(abase + ao + o, As[cur ^ 1] + o);
                gload16(bbase + bo + o, Bs[cur ^ 1] + o);
            }
        }
        // compute current chunk
#pragma unroll
        for (int ks = 0; ks < 2; ++ks) {
            const int ko = (ks * 64 + hi * 16) ^ sx;
            f16x8 af[4], bf[4];
#pragma unroll
            for (int ni = 0; ni < 4; ++ni)
                bf[ni] = *(const f16x8*)(Bs[cur] + (wc * 64 + ni * 16 + ln) * 128 + ko);
#pragma unroll
            for (int mi = 0; mi < 4; ++mi)
                af[mi] = *(const f16x8*)(As[cur] + (wr * 64 + mi * 16 + ln) * 128 + ko);
#pragma unroll
            for (int mi = 0; mi < 4; ++mi)
#pragma unroll
                for (int ni = 0; ni < 4; ++ni)
                    acc[mi][ni] = __builtin_amdgcn_mfma_f32_16x16x32_f16(
                        af[mi], bf[ni], acc[mi][ni], 0, 0, 0);
        }
        __syncthreads();  // drains vmcnt: next buffer ready; cur safe to overwrite
    }

    // ---- epilogue: dist + fused argmin
    float bnv[4];
#pragma unroll
    for (int ni = 0; ni < 4; ++ni)
        bnv[ni] = Bn[c0 + wc * 64 + ni * 16 + ln];
    const int rbase = row0 + wr * 64 + hi * 4;

#pragma unroll
    for (int mi = 0; mi < 4; ++mi) {
#pragma unroll
        for (int r = 0; r < 4; ++r) {
            float an = An[rbase + mi * 16 + r];
            unsigned long long best = ~0ull;
#pragma unroll
            for (int ni = 0; ni < 4; ++ni) {
                float sim  = acc[mi][ni][r] * 0x1p-20f;   // exact descale
                float t    = an + bnv[ni];
                float dist = t - 2.0f * sim;
                unsigned code = (unsigned)(c0 + wc * 64 + ni * 16 + ln);
                unsigned long long p =
                    ((unsigned long long)__float_as_uint(dist) << 32) | code;
                best = p < best ? p : best;
            }
#pragma unroll
            for (int mm = 1; mm < 16; mm <<= 1) {
                unsigned long long o = __shfl_xor(best, mm);
                best = o < best ? o : best;
            }
            if (ln == 0) atomicMin(&bests[rbase + mi * 16 + r], best);
        }
    }
}

// ---------------------------------------------------------------- gather + loss partials
__global__ void vq_gather(const float* __restrict__ x, const float* __restrict__ et,
                          const unsigned long long* __restrict__ bests,
                          float* __restrict__ out, float* __restrict__ part) {
    __shared__ float wsum[4];
    int w    = threadIdx.x >> 6;
    int lane = threadIdx.x & 63;
    int row  = blockIdx.x * 4 + w;
    int k    = (int)(unsigned)(bests[row] & 0xffffffffull);
    float4 q  = *(const float4*)&et[(size_t)k * DIM + lane * 4];
    float4 xv = *(const float4*)&x[(size_t)row * DIM + lane * 4];
    *(float4*)&out[(size_t)row * DIM + lane * 4] = q;
    float d0 = q.x - xv.x, d1 = q.y - xv.y, d2 = q.z - xv.z, d3 = q.w - xv.w;
    float s = d0 * d0 + d1 * d1 + d2 * d2 + d3 * d3;
#pragma unroll
    for (int m = 1; m < 64; m <<= 1) s += __shfl_xor(s, m);
    if (lane == 0) wsum[w] = s;
    __syncthreads();
    if (threadIdx.x == 0) part[blockIdx.x] = wsum[0] + wsum[1] + wsum[2] + wsum[3];
}

// ---------------------------------------------------------------- finalize loss
__global__ void vq_finalize(const float* __restrict__ part, float* __restrict__ lossOut) {
    __shared__ float sm[256];
    float s = 0.0f;
    for (int i = threadIdx.x; i < 8192; i += 256) s += part[i];
    sm[threadIdx.x] = s;
    __syncthreads();
    for (int st = 128; st > 0; st >>= 1) {
        if (threadIdx.x < st) sm[threadIdx.x] += sm[threadIdx.x + st];
        __syncthreads();
    }
    if (threadIdx.x == 0)
        lossOut[0] = 1.25f * (sm[0] / 8388608.0f);
}

// ---------------------------------------------------------------- launch
extern "C" void kernel_launch(void* const* d_in, const int* in_sizes, int n_in,
                              void* d_out, int out_size, void* d_ws, size_t ws_size,
                              hipStream_t stream) {
    const float* x = (const float*)d_in[0];   // [32768, 256]
    const float* e = (const float*)d_in[1];   // [256, 4096]
    float* out = (float*)d_out;
    float* ws  = (float*)d_ws;

    float* et   = ws + WS_ET;
    float* bn   = ws + WS_BN;
    float* an   = ws + WS_AN;
    float* part = ws + WS_PART;
    unsigned long long* bests = (unsigned long long*)(ws + WS_BEST);
    char*  Bp   = (char*)(ws + WS_BP);
    char*  Ap   = (char*)(ws + WS_AP);

    vq_prep_a<<<256, 256, 0, stream>>>(x, Ap, an);
    vq_prep_b<<<128, 256, 0, stream>>>(e, Bp);
    vq_transpose<<<dim3(KCODES / 32, DIM / 32), 256, 0, stream>>>(e, et);
    vq_rownorm<<<KCODES / 4, 256, 0, stream>>>(et, bn, KCODES);
    vq_init<<<N_ROWS / 256, 256, 0, stream>>>(bests);
    vq_main<<<8192, 256, 0, stream>>>(Ap, Bp, an, bn, bests);
    vq_gather<<<N_ROWS / 4, 256, 0, stream>>>(x, et, bests, out, part);
    vq_finalize<<<1, 256, 0, stream>>>(part, out + (size_t)N_ROWS * DIM);
}

// Round 5
// 403.826 us; speedup vs baseline: 1.0270x; 1.0270x over previous
//
#include <hip/hip_runtime.h>
#include <math.h>

typedef _Float16 f16;
typedef f16 f16x8 __attribute__((ext_vector_type(8)));
typedef float f32x4 __attribute__((ext_vector_type(4)));

#define N_ROWS 32768
#define DIM    256
#define KCODES 4096

// ws layout (float units)
#define WS_ET    0                           // et [4096][256] f32        (4 MB)
#define WS_BN    (WS_ET + KCODES*DIM)        // code norms [4096]
#define WS_AN    (WS_BN + KCODES)            // row norms [32768]
#define WS_PART  (WS_AN + N_ROWS)            // loss partials [8192]
#define WS_BEST  (WS_PART + 8192)            // u64 bests [32768] = 65536 floats
#define WS_BP    (WS_BEST + 65536)           // B' images  4 MB = 1048576 floats
#define WS_AP    (WS_BP + 1048576)           // A' images 32 MB = 8388608 floats

// Image geometry: one chunk = [128 rows][64 f16 = 128 B], swizzled:
//   byte_in_row = (dd*2) ^ ((row & 7) << 4)
// Per-rb A' block: 131072 B  (H plane @0: 4 chunks x 16384; L plane @65536)
// Per-jb B' block: 131072 B  (EH plane @0; EL plane @65536)
//
// sim*2^20 = H.EH + L.EH + H.EL  -> 12 uniform BK=64 chunks:
//   c in [0,4):  A=H chunk c,   B=EH chunk c
//   c in [4,8):  A=L chunk c-4, B=EH chunk c-4
//   c in [8,12): A=H chunk c-8, B=EL chunk c-8

// ---------------------------------------------------------------- helpers
__device__ __forceinline__ void gload16(const void* g, void* l) {
#if __has_builtin(__builtin_amdgcn_global_load_lds)
    __builtin_amdgcn_global_load_lds(
        (const __attribute__((address_space(1))) unsigned int*)g,
        (__attribute__((address_space(3))) unsigned int*)l, 16, 0, 0);
#else
    *(float4*)l = *(const float4*)g;
#endif
}

__device__ __forceinline__ constexpr int aoff_of(int c) {
    return (c & 3) * 16384 + (((c >> 2) == 1) ? 65536 : 0);
}
__device__ __forceinline__ constexpr int boff_of(int c) {
    return (c & 3) * 16384 + (((c >> 2) == 2) ? 65536 : 0);
}

// ---------------------------------------------------------------- transpose (for gather + bn)
__global__ void vq_transpose(const float* __restrict__ e, float* __restrict__ et) {
    __shared__ float tile[32][33];
    int x = threadIdx.x & 31;
    int y = threadIdx.x >> 5;
    int k0 = blockIdx.x * 32;
    int d0 = blockIdx.y * 32;
#pragma unroll
    for (int yy = 0; yy < 32; yy += 8)
        tile[y + yy][x] = e[(d0 + y + yy) * KCODES + k0 + x];
    __syncthreads();
#pragma unroll
    for (int yy = 0; yy < 32; yy += 8)
        et[(k0 + y + yy) * DIM + d0 + x] = tile[x][y + yy];
}

// ---------------------------------------------------------------- row norms (codes)
__global__ void vq_rownorm(const float* __restrict__ src, float* __restrict__ out, int nrows) {
    int w    = threadIdx.x >> 6;
    int lane = threadIdx.x & 63;
    int row  = blockIdx.x * 4 + w;
    if (row >= nrows) return;
    float4 v = *(const float4*)&src[row * DIM + lane * 4];
    float  s = v.x * v.x + v.y * v.y + v.z * v.z + v.w * v.w;
#pragma unroll
    for (int m = 1; m < 64; m <<= 1) s += __shfl_xor(s, m);
    if (lane == 0) out[row] = s;
}

// ---------------------------------------------------------------- A' prep (+ fused x row norms)
__global__ void vq_prep_a(const float* __restrict__ x, char* __restrict__ Ap,
                          float* __restrict__ An) {
    const int t = threadIdx.x;
    const int lane = t & 63, w = t >> 6;
    const size_t row0 = (size_t)blockIdx.x * 128;
    char* base = Ap + (size_t)blockIdx.x * 131072;
    const int chunk = lane >> 4;
    const int dd2   = (lane & 15) * 8;       // byte offset of 4 f16
#pragma unroll 4
    for (int it = 0; it < 32; ++it) {
        const int m = it * 4 + w;
        float4 v = *(const float4*)&x[(row0 + m) * DIM + lane * 4];
        float vs[4] = { v.x, v.y, v.z, v.w };
        uint32_t hw[2], lw[2];
#pragma unroll
        for (int p = 0; p < 2; ++p) {
            uint32_t hword = 0, lword = 0;
#pragma unroll
            for (int j = 0; j < 2; ++j) {
                float s = vs[p * 2 + j] * 1024.0f;
                f16 h = (f16)s;
                f16 l = (f16)(s - (float)h);
                hword |= (uint32_t)__builtin_bit_cast(uint16_t, h) << (16 * j);
                lword |= (uint32_t)__builtin_bit_cast(uint16_t, l) << (16 * j);
            }
            hw[p] = hword; lw[p] = lword;
        }
        const int off = chunk * 16384 + m * 128 + (dd2 ^ ((m & 7) << 4));
        *(uint2*)(base + off)         = *(uint2*)hw;
        *(uint2*)(base + 65536 + off) = *(uint2*)lw;
        // fused row norm
        float s = v.x * v.x + v.y * v.y + v.z * v.z + v.w * v.w;
#pragma unroll
        for (int mm = 1; mm < 64; mm <<= 1) s += __shfl_xor(s, mm);
        if (lane == 0) An[row0 + m] = s;
    }
}

// ---------------------------------------------------------------- B' prep
__global__ void vq_prep_b(const float* __restrict__ e, char* __restrict__ Bp) {
    __shared__ float lt[128][65];   // [n_loc][dd]
    const int t  = threadIdx.x;
    const int jb = blockIdx.x >> 2;
    const int c  = blockIdx.x & 3;
    const int d0 = c * 64, n0 = jb * 128;
#pragma unroll
    for (int it = 0; it < 8; ++it) {
        int linear = it * 256 + t;
        int drow = linear >> 5;
        int ncol = (linear & 31) * 4;
        float4 v = *(const float4*)&e[(size_t)(d0 + drow) * KCODES + n0 + ncol];
        lt[ncol + 0][drow] = v.x;
        lt[ncol + 1][drow] = v.y;
        lt[ncol + 2][drow] = v.z;
        lt[ncol + 3][drow] = v.w;
    }
    __syncthreads();
    char* ehbase = Bp + (size_t)jb * 131072 + c * 16384;
    const int n_loc = t >> 1;
    const int shalf = t & 1;
#pragma unroll
    for (int g = 0; g < 4; ++g) {
        const int dd8 = shalf * 32 + g * 8;
        uint32_t ehw[4], elw[4];
#pragma unroll
        for (int p = 0; p < 4; ++p) {
            uint32_t hword = 0, lword = 0;
#pragma unroll
            for (int j = 0; j < 2; ++j) {
                float s = lt[n_loc][dd8 + p * 2 + j] * 1024.0f;
                f16 h = (f16)s;
                f16 l = (f16)(s - (float)h);
                hword |= (uint32_t)__builtin_bit_cast(uint16_t, h) << (16 * j);
                lword |= (uint32_t)__builtin_bit_cast(uint16_t, l) << (16 * j);
            }
            ehw[p] = hword; elw[p] = lword;
        }
        const int off = n_loc * 128 + ((dd8 * 2) ^ ((n_loc & 7) << 4));
        *(uint4*)(ehbase + off)         = *(uint4*)ehw;
        *(uint4*)(ehbase + 65536 + off) = *(uint4*)elw;
    }
}

// ---------------------------------------------------------------- init bests
__global__ void vq_init(unsigned long long* __restrict__ bests) {
    int i = blockIdx.x * 256 + threadIdx.x;
    if (i < N_ROWS) bests[i] = ~0ull;
}

// ---------------------------------------------------------------- main MFMA GEMM + argmin
// m97 geometry: 128x128 tile, 4 waves, single-buffered 32 KB LDS, 2 barriers
// per BK=64 chunk. TLP (~5 blocks/CU) hides staging latency.
__global__ __launch_bounds__(256) void vq_main(
    const char* __restrict__ Ap, const char* __restrict__ Bp,
    const float* __restrict__ An, const float* __restrict__ Bn,
    unsigned long long* __restrict__ bests)
{
    __shared__ __align__(16) char As[16384];
    __shared__ __align__(16) char Bs[16384];

    const int tid  = threadIdx.x;
    const int wid  = tid >> 6, lane = tid & 63;
    const int wr   = wid >> 1, wc = wid & 1;
    const int rb   = blockIdx.x & 255, jb = blockIdx.x >> 8;
    const int row0 = rb * 128, c0 = jb * 128;
    const int hi = lane >> 4, ln = lane & 15;
    const int sx = (lane & 7) << 4;

    const char* abase = Ap + (size_t)rb * 131072;
    const char* bbase = Bp + (size_t)jb * 131072;

    f32x4 acc[4][4] = {};

#pragma unroll
    for (int c = 0; c < 12; ++c) {
        if (c) __syncthreads();          // prior compute done reading LDS
        const int ao = aoff_of(c), bo = boff_of(c);
#pragma unroll
        for (int it = 0; it < 4; ++it) {
            const int o = it * 4096 + tid * 16;
            gload16(abase + ao + o, As + o);
            gload16(bbase + bo + o, Bs + o);
        }
        __syncthreads();                 // staging landed (barrier drains vmcnt)

#pragma unroll
        for (int ks = 0; ks < 2; ++ks) {
            const int ko = (ks * 64 + hi * 16) ^ sx;
            f16x8 af[4], bf[4];
#pragma unroll
            for (int ni = 0; ni < 4; ++ni)
                bf[ni] = *(const f16x8*)(Bs + (wc * 64 + ni * 16 + ln) * 128 + ko);
#pragma unroll
            for (int mi = 0; mi < 4; ++mi)
                af[mi] = *(const f16x8*)(As + (wr * 64 + mi * 16 + ln) * 128 + ko);
#pragma unroll
            for (int mi = 0; mi < 4; ++mi)
#pragma unroll
                for (int ni = 0; ni < 4; ++ni)
                    acc[mi][ni] = __builtin_amdgcn_mfma_f32_16x16x32_f16(
                        af[mi], bf[ni], acc[mi][ni], 0, 0, 0);
        }
    }

    // ---- epilogue: dist + fused argmin
    float bnv[4];
#pragma unroll
    for (int ni = 0; ni < 4; ++ni)
        bnv[ni] = Bn[c0 + wc * 64 + ni * 16 + ln];
    const int rbase = row0 + wr * 64 + hi * 4;

#pragma unroll
    for (int mi = 0; mi < 4; ++mi) {
#pragma unroll
        for (int r = 0; r < 4; ++r) {
            float an = An[rbase + mi * 16 + r];
            unsigned long long best = ~0ull;
#pragma unroll
            for (int ni = 0; ni < 4; ++ni) {
                float sim  = acc[mi][ni][r] * 0x1p-20f;   // exact descale
                float t    = an + bnv[ni];
                float dist = t - 2.0f * sim;
                unsigned code = (unsigned)(c0 + wc * 64 + ni * 16 + ln);
                unsigned long long p =
                    ((unsigned long long)__float_as_uint(dist) << 32) | code;
                best = p < best ? p : best;
            }
#pragma unroll
            for (int mm = 1; mm < 16; mm <<= 1) {
                unsigned long long o = __shfl_xor(best, mm);
                best = o < best ? o : best;
            }
            if (ln == 0) atomicMin(&bests[rbase + mi * 16 + r], best);
        }
    }
}

// ---------------------------------------------------------------- gather + loss partials
__global__ void vq_gather(const float* __restrict__ x, const float* __restrict__ et,
                          const unsigned long long* __restrict__ bests,
                          float* __restrict__ out, float* __restrict__ part) {
    __shared__ float wsum[4];
    int w    = threadIdx.x >> 6;
    int lane = threadIdx.x & 63;
    int row  = blockIdx.x * 4 + w;
    int k    = (int)(unsigned)(bests[row] & 0xffffffffull);
    float4 q  = *(const float4*)&et[(size_t)k * DIM + lane * 4];
    float4 xv = *(const float4*)&x[(size_t)row * DIM + lane * 4];
    *(float4*)&out[(size_t)row * DIM + lane * 4] = q;
    float d0 = q.x - xv.x, d1 = q.y - xv.y, d2 = q.z - xv.z, d3 = q.w - xv.w;
    float s = d0 * d0 + d1 * d1 + d2 * d2 + d3 * d3;
#pragma unroll
    for (int m = 1; m < 64; m <<= 1) s += __shfl_xor(s, m);
    if (lane == 0) wsum[w] = s;
    __syncthreads();
    if (threadIdx.x == 0) part[blockIdx.x] = wsum[0] + wsum[1] + wsum[2] + wsum[3];
}

// ---------------------------------------------------------------- finalize loss
__global__ void vq_finalize(const float* __restrict__ part, float* __restrict__ lossOut) {
    __shared__ float sm[256];
    float s = 0.0f;
    for (int i = threadIdx.x; i < 8192; i += 256) s += part[i];
    sm[threadIdx.x] = s;
    __syncthreads();
    for (int st = 128; st > 0; st >>= 1) {
        if (threadIdx.x < st) sm[threadIdx.x] += sm[threadIdx.x + st];
        __syncthreads();
    }
    if (threadIdx.x == 0)
        lossOut[0] = 1.25f * (sm[0] / 8388608.0f);
}

// ---------------------------------------------------------------- launch
extern "C" void kernel_launch(void* const* d_in, const int* in_sizes, int n_in,
                              void* d_out, int out_size, void* d_ws, size_t ws_size,
                              hipStream_t stream) {
    const float* x = (const float*)d_in[0];   // [32768, 256]
    const float* e = (const float*)d_in[1];   // [256, 4096]
    float* out = (float*)d_out;
    float* ws  = (float*)d_ws;

    float* et   = ws + WS_ET;
    float* bn   = ws + WS_BN;
    float* an   = ws + WS_AN;
    float* part = ws + WS_PART;
    unsigned long long* bests = (unsigned long long*)(ws + WS_BEST);
    char*  Bp   = (char*)(ws + WS_BP);
    char*  Ap   = (char*)(ws + WS_AP);

    vq_prep_a<<<256, 256, 0, stream>>>(x, Ap, an);
    vq_prep_b<<<128, 256, 0, stream>>>(e, Bp);
    vq_transpose<<<dim3(KCODES / 32, DIM / 32), 256, 0, stream>>>(e, et);
    vq_rownorm<<<KCODES / 4, 256, 0, stream>>>(et, bn, KCODES);
    vq_init<<<N_ROWS / 256, 256, 0, stream>>>(bests);
    vq_main<<<8192, 256, 0, stream>>>(Ap, Bp, an, bn, bests);
    vq_gather<<<N_ROWS / 4, 256, 0, stream>>>(x, et, bests, out, part);
    vq_finalize<<<1, 256, 0, stream>>>(part, out + (size_t)N_ROWS * DIM);
}

// Round 6
// 342.201 us; speedup vs baseline: 1.2120x; 1.1801x over previous
//
#include <hip/hip_runtime.h>
#include <math.h>

typedef _Float16 f16;
typedef f16 f16x8 __attribute__((ext_vector_type(8)));
typedef float f32x4 __attribute__((ext_vector_type(4)));

#define N_ROWS 32768
#define DIM    256
#define KCODES 4096

// ws layout (float units)
#define WS_ET    0                           // et [4096][256] f32        (4 MB)
#define WS_BN    (WS_ET + KCODES*DIM)        // code norms [4096]
#define WS_AN    (WS_BN + KCODES)            // row norms [32768]
#define WS_PART  (WS_AN + N_ROWS)            // loss partials [8192]
#define WS_BEST  (WS_PART + 8192)            // u64 bests [32768] = 65536 floats
#define WS_BP    (WS_BEST + 65536)           // B' images  4 MB = 1048576 floats
#define WS_AP    (WS_BP + 1048576)           // A' images 32 MB = 8388608 floats

// Image geometry (unchanged from R3): one chunk = [128 rows][64 f16 = 128 B],
// swizzled: byte_in_row = (dd*2) ^ ((row & 7) << 4)
// Per-128-row A' block: 131072 B (H plane @0: 4 chunks x 16384; L @65536)
// Per-128-code B' block: 131072 B (EH @0; EL @65536)
// sim*2^20 = H.EH + L.EH + H.EL (l*l dropped, ~4e-7 in dist units)

// ---------------------------------------------------------------- helpers
__device__ __forceinline__ void gload16(const void* g, void* l) {
#if __has_builtin(__builtin_amdgcn_global_load_lds)
    __builtin_amdgcn_global_load_lds(
        (const __attribute__((address_space(1))) unsigned int*)g,
        (__attribute__((address_space(3))) unsigned int*)l, 16, 0, 0);
#else
    *(float4*)l = *(const float4*)g;
#endif
}

// ---------------------------------------------------------------- row norms (codes)
__global__ void vq_rownorm(const float* __restrict__ src, float* __restrict__ out, int nrows) {
    int w    = threadIdx.x >> 6;
    int lane = threadIdx.x & 63;
    int row  = blockIdx.x * 4 + w;
    if (row >= nrows) return;
    float4 v = *(const float4*)&src[row * DIM + lane * 4];
    float  s = v.x * v.x + v.y * v.y + v.z * v.z + v.w * v.w;
#pragma unroll
    for (int m = 1; m < 64; m <<= 1) s += __shfl_xor(s, m);
    if (lane == 0) out[row] = s;
}

// ---------------------------------------------------------------- A' prep (+ fused x row norms)
__global__ void vq_prep_a(const float* __restrict__ x, char* __restrict__ Ap,
                          float* __restrict__ An) {
    const int t = threadIdx.x;
    const int lane = t & 63, w = t >> 6;
    const size_t row0 = (size_t)blockIdx.x * 128;
    char* base = Ap + (size_t)blockIdx.x * 131072;
    const int chunk = lane >> 4;
    const int dd2   = (lane & 15) * 8;       // byte offset of 4 f16
#pragma unroll 4
    for (int it = 0; it < 32; ++it) {
        const int m = it * 4 + w;
        float4 v = *(const float4*)&x[(row0 + m) * DIM + lane * 4];
        float vs[4] = { v.x, v.y, v.z, v.w };
        uint32_t hw[2], lw[2];
#pragma unroll
        for (int p = 0; p < 2; ++p) {
            uint32_t hword = 0, lword = 0;
#pragma unroll
            for (int j = 0; j < 2; ++j) {
                float s = vs[p * 2 + j] * 1024.0f;
                f16 h = (f16)s;
                f16 l = (f16)(s - (float)h);
                hword |= (uint32_t)__builtin_bit_cast(uint16_t, h) << (16 * j);
                lword |= (uint32_t)__builtin_bit_cast(uint16_t, l) << (16 * j);
            }
            hw[p] = hword; lw[p] = lword;
        }
        const int off = chunk * 16384 + m * 128 + (dd2 ^ ((m & 7) << 4));
        *(uint2*)(base + off)         = *(uint2*)hw;
        *(uint2*)(base + 65536 + off) = *(uint2*)lw;
        float s = v.x * v.x + v.y * v.y + v.z * v.z + v.w * v.w;
#pragma unroll
        for (int mm = 1; mm < 64; mm <<= 1) s += __shfl_xor(s, mm);
        if (lane == 0) An[row0 + m] = s;
    }
}

// ---------------------------------------------------------------- B' prep (+ writes et)
__global__ void vq_prep_b(const float* __restrict__ e, char* __restrict__ Bp,
                          float* __restrict__ et) {
    __shared__ float lt[128][65];   // [n_loc][dd]
    const int t  = threadIdx.x;
    const int jb = blockIdx.x >> 2;
    const int c  = blockIdx.x & 3;
    const int d0 = c * 64, n0 = jb * 128;
#pragma unroll
    for (int it = 0; it < 8; ++it) {
        int linear = it * 256 + t;
        int drow = linear >> 5;
        int ncol = (linear & 31) * 4;
        float4 v = *(const float4*)&e[(size_t)(d0 + drow) * KCODES + n0 + ncol];
        lt[ncol + 0][drow] = v.x;
        lt[ncol + 1][drow] = v.y;
        lt[ncol + 2][drow] = v.z;
        lt[ncol + 3][drow] = v.w;
    }
    __syncthreads();
    // transposed slab -> et (replaces vq_transpose)
#pragma unroll
    for (int it = 0; it < 8; ++it) {
        int lin = it * 256 + t;          // 128 n x 16 q
        int n = lin >> 4, q = lin & 15;
        float4 v = { lt[n][q*4], lt[n][q*4+1], lt[n][q*4+2], lt[n][q*4+3] };
        *(float4*)&et[(size_t)(n0 + n) * DIM + d0 + q * 4] = v;
    }
    char* ehbase = Bp + (size_t)jb * 131072 + c * 16384;
    const int n_loc = t >> 1;
    const int shalf = t & 1;
#pragma unroll
    for (int g = 0; g < 4; ++g) {
        const int dd8 = shalf * 32 + g * 8;
        uint32_t ehw[4], elw[4];
#pragma unroll
        for (int p = 0; p < 4; ++p) {
            uint32_t hword = 0, lword = 0;
#pragma unroll
            for (int j = 0; j < 2; ++j) {
                float s = lt[n_loc][dd8 + p * 2 + j] * 1024.0f;
                f16 h = (f16)s;
                f16 l = (f16)(s - (float)h);
                hword |= (uint32_t)__builtin_bit_cast(uint16_t, h) << (16 * j);
                lword |= (uint32_t)__builtin_bit_cast(uint16_t, l) << (16 * j);
            }
            ehw[p] = hword; elw[p] = lword;
        }
        const int off = n_loc * 128 + ((dd8 * 2) ^ ((n_loc & 7) << 4));
        *(uint4*)(ehbase + off)         = *(uint4*)ehw;
        *(uint4*)(ehbase + 65536 + off) = *(uint4*)elw;
    }
}

// ---------------------------------------------------------------- init bests
__global__ void vq_init(unsigned long long* __restrict__ bests) {
    int i = blockIdx.x * 256 + threadIdx.x;
    if (i < N_ROWS) bests[i] = ~0ull;
}

// ---------------------------------------------------------------- main MFMA GEMM + argmin
// 256x256 tile, 512 threads, 8 waves (2 row x 4 col), per-wave 128x64.
// Per chunk c (BK=64): stage all 4 planes x 2 halves (128 KB), 2 barriers,
// then 192 MFMA/wave (3 split-terms x 8mi x 4ni x 2ks).
__global__ __launch_bounds__(512, 2) void vq_main(
    const char* __restrict__ Ap, const char* __restrict__ Bp,
    const float* __restrict__ An, const float* __restrict__ Bn,
    unsigned long long* __restrict__ bests)
{
    __shared__ __align__(16) char As[2][2][16384];   // [row-half][H/L]
    __shared__ __align__(16) char Bs[2][2][16384];   // [col-half][EH/EL]

    const int tid  = threadIdx.x;
    const int wid  = tid >> 6, lane = tid & 63;
    const int wr   = wid >> 2, wc = wid & 3;          // 2 x 4 waves
    const int rb   = blockIdx.x & 127, jb = blockIdx.x >> 7;
    const int row0 = rb * 256, c0 = jb * 256;
    const int hi = lane >> 4, ln = lane & 15;
    const int sx = (lane & 7) << 4;

    const char* a0 = Ap + (size_t)(2 * rb) * 131072;
    const char* a1 = a0 + 131072;
    const char* b0 = Bp + (size_t)(2 * jb) * 131072;
    const char* b1 = b0 + 131072;

    f32x4 acc[8][4] = {};

    const int brow = (wc & 1) * 64;       // within col-half
    const char* myA = As[wr][0];          // base for this wave's row-half
    const char* myAL = As[wr][1];
    const char* myB = Bs[wc >> 1][0];
    const char* myBL = Bs[wc >> 1][1];

#pragma unroll 1
    for (int c = 0; c < 4; ++c) {
        if (c) __syncthreads();
        const int co = c * 16384;
#pragma unroll
        for (int r = 0; r < 2; ++r) {
            const int o = r * 8192 + tid * 16;
            gload16(a0 + co + o,         &As[0][0][o]);
            gload16(a0 + 65536 + co + o, &As[0][1][o]);
            gload16(a1 + co + o,         &As[1][0][o]);
            gload16(a1 + 65536 + co + o, &As[1][1][o]);
            gload16(b0 + co + o,         &Bs[0][0][o]);
            gload16(b0 + 65536 + co + o, &Bs[0][1][o]);
            gload16(b1 + co + o,         &Bs[1][0][o]);
            gload16(b1 + 65536 + co + o, &Bs[1][1][o]);
        }
        __syncthreads();   // staging landed (barrier drains vmcnt)

#pragma unroll
        for (int ks = 0; ks < 2; ++ks) {
            const int ko = (ks * 64 + hi * 16) ^ sx;
            f16x8 ah[8], al[8], bh[4], bl[4];
#pragma unroll
            for (int mi = 0; mi < 8; ++mi) {
                ah[mi] = *(const f16x8*)(myA  + (mi * 16 + ln) * 128 + ko);
                al[mi] = *(const f16x8*)(myAL + (mi * 16 + ln) * 128 + ko);
            }
#pragma unroll
            for (int ni = 0; ni < 4; ++ni) {
                const int r = brow + ni * 16 + ln;
                bh[ni] = *(const f16x8*)(myB  + r * 128 + ko);
                bl[ni] = *(const f16x8*)(myBL + r * 128 + ko);
            }
#pragma unroll
            for (int mi = 0; mi < 8; ++mi)
#pragma unroll
                for (int ni = 0; ni < 4; ++ni)
                    acc[mi][ni] = __builtin_amdgcn_mfma_f32_16x16x32_f16(
                        ah[mi], bh[ni], acc[mi][ni], 0, 0, 0);
#pragma unroll
            for (int mi = 0; mi < 8; ++mi)
#pragma unroll
                for (int ni = 0; ni < 4; ++ni)
                    acc[mi][ni] = __builtin_amdgcn_mfma_f32_16x16x32_f16(
                        al[mi], bh[ni], acc[mi][ni], 0, 0, 0);
#pragma unroll
            for (int mi = 0; mi < 8; ++mi)
#pragma unroll
                for (int ni = 0; ni < 4; ++ni)
                    acc[mi][ni] = __builtin_amdgcn_mfma_f32_16x16x32_f16(
                        ah[mi], bl[ni], acc[mi][ni], 0, 0, 0);
        }
    }

    // ---- epilogue: dist + fused argmin
    float bnv[4];
#pragma unroll
    for (int ni = 0; ni < 4; ++ni)
        bnv[ni] = Bn[c0 + wc * 64 + ni * 16 + ln];
    const int rbase = row0 + wr * 128 + hi * 4;

#pragma unroll
    for (int mi = 0; mi < 8; ++mi) {
#pragma unroll
        for (int r = 0; r < 4; ++r) {
            float an = An[rbase + mi * 16 + r];
            unsigned long long best = ~0ull;
#pragma unroll
            for (int ni = 0; ni < 4; ++ni) {
                float sim  = acc[mi][ni][r] * 0x1p-20f;   // exact descale
                float t    = an + bnv[ni];
                float dist = t - 2.0f * sim;
                unsigned code = (unsigned)(c0 + wc * 64 + ni * 16 + ln);
                unsigned long long p =
                    ((unsigned long long)__float_as_uint(dist) << 32) | code;
                best = p < best ? p : best;
            }
#pragma unroll
            for (int mm = 1; mm < 16; mm <<= 1) {
                unsigned long long o = __shfl_xor(best, mm);
                best = o < best ? o : best;
            }
            if (ln == 0) atomicMin(&bests[rbase + mi * 16 + r], best);
        }
    }
}

// ---------------------------------------------------------------- gather + loss partials
__global__ void vq_gather(const float* __restrict__ x, const float* __restrict__ et,
                          const unsigned long long* __restrict__ bests,
                          float* __restrict__ out, float* __restrict__ part) {
    __shared__ float wsum[4];
    int w    = threadIdx.x >> 6;
    int lane = threadIdx.x & 63;
    int row  = blockIdx.x * 4 + w;
    int k    = (int)(unsigned)(bests[row] & 0xffffffffull);
    float4 q  = *(const float4*)&et[(size_t)k * DIM + lane * 4];
    float4 xv = *(const float4*)&x[(size_t)row * DIM + lane * 4];
    *(float4*)&out[(size_t)row * DIM + lane * 4] = q;
    float d0 = q.x - xv.x, d1 = q.y - xv.y, d2 = q.z - xv.z, d3 = q.w - xv.w;
    float s = d0 * d0 + d1 * d1 + d2 * d2 + d3 * d3;
#pragma unroll
    for (int m = 1; m < 64; m <<= 1) s += __shfl_xor(s, m);
    if (lane == 0) wsum[w] = s;
    __syncthreads();
    if (threadIdx.x == 0) part[blockIdx.x] = wsum[0] + wsum[1] + wsum[2] + wsum[3];
}

// ---------------------------------------------------------------- finalize loss
__global__ void vq_finalize(const float* __restrict__ part, float* __restrict__ lossOut) {
    __shared__ float sm[256];
    float s = 0.0f;
    for (int i = threadIdx.x; i < 8192; i += 256) s += part[i];
    sm[threadIdx.x] = s;
    __syncthreads();
    for (int st = 128; st > 0; st >>= 1) {
        if (threadIdx.x < st) sm[threadIdx.x] += sm[threadIdx.x + st];
        __syncthreads();
    }
    if (threadIdx.x == 0)
        lossOut[0] = 1.25f * (sm[0] / 8388608.0f);
}

// ---------------------------------------------------------------- launch
extern "C" void kernel_launch(void* const* d_in, const int* in_sizes, int n_in,
                              void* d_out, int out_size, void* d_ws, size_t ws_size,
                              hipStream_t stream) {
    const float* x = (const float*)d_in[0];   // [32768, 256]
    const float* e = (const float*)d_in[1];   // [256, 4096]
    float* out = (float*)d_out;
    float* ws  = (float*)d_ws;

    float* et   = ws + WS_ET;
    float* bn   = ws + WS_BN;
    float* an   = ws + WS_AN;
    float* part = ws + WS_PART;
    unsigned long long* bests = (unsigned long long*)(ws + WS_BEST);
    char*  Bp   = (char*)(ws + WS_BP);
    char*  Ap   = (char*)(ws + WS_AP);

    vq_prep_a<<<256, 256, 0, stream>>>(x, Ap, an);
    vq_prep_b<<<128, 256, 0, stream>>>(e, Bp, et);
    vq_rownorm<<<KCODES / 4, 256, 0, stream>>>(et, bn, KCODES);
    vq_init<<<N_ROWS / 256, 256, 0, stream>>>(bests);
    vq_main<<<2048, 512, 0, stream>>>(Ap, Bp, an, bn, bests);
    vq_gather<<<N_ROWS / 4, 256, 0, stream>>>(x, et, bests, out, part);
    vq_finalize<<<1, 256, 0, stream>>>(part, out + (size_t)N_ROWS * DIM);
}